// Round 1
// 132.845 us; speedup vs baseline: 1.1008x; 1.1008x over previous
//
#include <hip/hip_runtime.h>
#include <math.h>

// Problem dims
constexpr int K_ = 128, J_ = 4, R_ = 32, T_ = 32, S_ = 256, A_ = 4, D_ = 64;
constexpr int NDF_ = 128;          // 2N
constexpr float RATE_ = 10.0f;     // 1/PRIOR_BL

// Output offsets (float elements) in return order
constexpr int OFF_M1   = 0;                       // K x 33 (int->float)
constexpr int OFF_M2   = OFF_M1 + K_ * 33;
constexpr int OFF_B1   = OFF_M2 + K_ * 33;
constexpr int OFF_B2   = OFF_B1 + K_ * 33;
constexpr int OFF_EMBR = OFF_B2 + K_ * 33;        // K x 33 x 64
constexpr int OFF_LC   = OFF_EMBR + K_ * 33 * D_; // K x 31
constexpr int OFF_H    = OFF_LC + K_ * 31;
constexpr int OFF_EMBT = OFF_H + K_ * 31;         // K x 31 x 64
constexpr int OFF_LF   = OFF_EMBT + K_ * 31 * D_; // K x 31 x 256 x 4
constexpr int OFF_LPN  = OFF_LF + K_ * 31 * S_ * A_;
constexpr int OFF_LW   = OFF_LPN + K_;
constexpr int OFF_LL   = OFF_LW + K_;

// Workspace layout (float elements). Total ~85 KB.
constexpr int WS_NODE  = 0;                        // K*T node log-liks
constexpr int WS_NEWLL = WS_NODE + K_ * T_;        // K*J new-node log-liks
constexpr int WS_LOGP  = WS_NEWLL + K_ * J_;       // K*J*32 logP1|logP2
constexpr int WS_SUB   = WS_LOGP + K_ * J_ * 32;   // K ints (selected proposal)

// fast 4-way logsumexp: hardware exp/log
__device__ inline float lse4f(float a, float b, float c, float d) {
    float m = fmaxf(fmaxf(a, b), fmaxf(c, d));
    return m + __logf(__expf(a - m) + __expf(b - m) + __expf(c - m) + __expf(d - m));
}

// ============ Kernel 1: node log-liks + proposal log-liks ============
// grid (9, K): grp 0..7 -> node blocks (wave w owns t = grp*4+w)
//              grp == 8 -> proposal block (wave w owns proposal j = w)
__global__ __launch_bounds__(256) void k_compute(
    const int* __restrict__ indexes, const float* __restrict__ embt,
    const float* __restrict__ lf, const float* __restrict__ Wstat,
    const float* __restrict__ Wq, const int* __restrict__ idx1_KJ,
    const int* __restrict__ idx2_KJ, const float* __restrict__ br1_KJ,
    const float* __restrict__ br2_KJ, const float* __restrict__ emb_KJD,
    float* __restrict__ ws) {
    int grp = blockIdx.x;
    int k = blockIdx.y;
    int tid = threadIdx.x, w = tid >> 6, lane = tid & 63;
    int src = indexes[k];

    if (grp < 8) {
        // -------- node log-lik for t = grp*4 + w --------
        int t = grp * 4 + w;
        float e = embt[(src * T_ + t) * D_ + lane];
        const float4 w4 = *(const float4*)&Wstat[lane * 4];
        float g0 = e * w4.x, g1 = e * w4.y, g2 = e * w4.z, g3 = e * w4.w;
#pragma unroll
        for (int m = 32; m; m >>= 1) {
            g0 += __shfl_xor(g0, m, 64);
            g1 += __shfl_xor(g1, m, 64);
            g2 += __shfl_xor(g2, m, 64);
            g3 += __shfl_xor(g3, m, 64);
        }
        float lse = lse4f(g0, g1, g2, g3);
        float ls0 = g0 - lse, ls1 = g1 - lse, ls2 = g2 - lse, ls3 = g3 - lse;
        const float4* fr = (const float4*)&lf[(size_t)(src * T_ + t) * S_ * A_];
        double acc = 0.0;
#pragma unroll
        for (int s4 = 0; s4 < 4; ++s4) {
            float4 f = fr[s4 * 64 + lane];   // coalesced: 1KB per instruction
            acc += (double)lse4f(f.x + ls0, f.y + ls1, f.z + ls2, f.w + ls3);
        }
#pragma unroll
        for (int m = 32; m; m >>= 1) acc += __shfl_xor(acc, m, 64);
        if (lane == 0) ws[WS_NODE + k * T_ + t] = (float)acc;
    } else {
        // -------- proposal z = k*J + w --------
        int z = k * J_ + w;
        int i1 = idx1_KJ[z], i2 = idx2_KJ[z];

        // 20 logits (16 Wq + 4 Wstat) via one butterfly
        float emb_d = emb_KJD[z * D_ + lane];
        float lg[20];
        const float4* wqr = (const float4*)&Wq[lane * 16];
        float4 q0 = wqr[0], q1 = wqr[1], q2 = wqr[2], q3 = wqr[3];
        lg[0] = emb_d * q0.x;  lg[1] = emb_d * q0.y;  lg[2] = emb_d * q0.z;  lg[3] = emb_d * q0.w;
        lg[4] = emb_d * q1.x;  lg[5] = emb_d * q1.y;  lg[6] = emb_d * q1.z;  lg[7] = emb_d * q1.w;
        lg[8] = emb_d * q2.x;  lg[9] = emb_d * q2.y;  lg[10] = emb_d * q2.z; lg[11] = emb_d * q2.w;
        lg[12] = emb_d * q3.x; lg[13] = emb_d * q3.y; lg[14] = emb_d * q3.z; lg[15] = emb_d * q3.w;
        const float4 ws4 = *(const float4*)&Wstat[lane * 4];
        lg[16] = emb_d * ws4.x; lg[17] = emb_d * ws4.y; lg[18] = emb_d * ws4.z; lg[19] = emb_d * ws4.w;
#pragma unroll
        for (int m = 32; m; m >>= 1) {
#pragma unroll
            for (int p = 0; p < 20; ++p) lg[p] += __shfl_xor(lg[p], m, 64);
        }

        float lseS = lse4f(lg[16], lg[17], lg[18], lg[19]);
        float ls0 = lg[16] - lseS, ls1 = lg[17] - lseS, ls2 = lg[18] - lseS, ls3 = lg[19] - lseS;

        // expm (f32, fixed 2^-6 scaling + Taylor-10 + 6 squarings) on lanes 0..7
        float lv[4] = {0.f, 0.f, 0.f, 0.f};
        if (lane < 8) {
            int h = lane >> 2, r = lane & 3, base = h * 4;
            float q[16];
#pragma unroll
            for (int i = 0; i < 4; ++i) {
                float rs = 0.f;
#pragma unroll
                for (int j = 0; j < 4; ++j) {
                    if (i != j) {
                        float x = lg[i * 4 + j];
                        float sp = (x > 15.f) ? x : log1pf(__expf(x));
                        q[i * 4 + j] = sp;
                        rs += sp;
                    }
                }
                q[i * 4 + i] = -rs;
            }
            float br = (h == 0) ? br1_KJ[z] : br2_KJ[z];
            float c = br * (1.f / 64.f);
#pragma unroll
            for (int e2 = 0; e2 < 16; ++e2) q[e2] *= c;
            float trow[4], arow[4];
#pragma unroll
            for (int j = 0; j < 4; ++j) { trow[j] = (j == r) ? 1.f : 0.f; arow[j] = trow[j]; }
            const float inv_n[11] = {0.f, 1.f, 0.5f, 1.f / 3.f, 0.25f, 0.2f,
                                     1.f / 6.f, 1.f / 7.f, 0.125f, 1.f / 9.f, 0.1f};
#pragma unroll
            for (int n = 1; n <= 10; ++n) {
                float nt[4];
#pragma unroll
                for (int j = 0; j < 4; ++j)
                    nt[j] = (trow[0] * q[0 * 4 + j] + trow[1] * q[1 * 4 + j] +
                             trow[2] * q[2 * 4 + j] + trow[3] * q[3 * 4 + j]) * inv_n[n];
#pragma unroll
                for (int j = 0; j < 4; ++j) { trow[j] = nt[j]; arow[j] += nt[j]; }
            }
#pragma unroll
            for (int sq = 0; sq < 6; ++sq) {
                float nrow[4];
#pragma unroll
                for (int j = 0; j < 4; ++j) {
                    float aj = arow[j];
                    nrow[j] = arow[0] * __shfl(aj, base + 0, 64)
                            + arow[1] * __shfl(aj, base + 1, 64)
                            + arow[2] * __shfl(aj, base + 2, 64)
                            + arow[3] * __shfl(aj, base + 3, 64);
                }
#pragma unroll
                for (int j = 0; j < 4; ++j) arow[j] = nrow[j];
            }
#pragma unroll
            for (int j = 0; j < 4; ++j) {
                lv[j] = __logf(fmaxf(arow[j], 1e-30f));
                ws[WS_LOGP + z * 32 + h * 16 + r * 4 + j] = lv[j];
            }
        }
        // broadcast logP to all lanes (p1 rows in lanes 0..3, p2 in lanes 4..7)
        float p1[16], p2[16];
#pragma unroll
        for (int r = 0; r < 4; ++r) {
#pragma unroll
            for (int j = 0; j < 4; ++j) {
                p1[r * 4 + j] = __shfl(lv[j], r, 64);
                p2[r * 4 + j] = __shfl(lv[j], 4 + r, 64);
            }
        }
        // new-node log-lik over sites
        const float4* f1p = (const float4*)&lf[(size_t)(src * T_ + i1) * S_ * A_];
        const float4* f2p = (const float4*)&lf[(size_t)(src * T_ + i2) * S_ * A_];
        double acc = 0.0;
#pragma unroll
        for (int s4 = 0; s4 < 4; ++s4) {
            float4 f = f1p[s4 * 64 + lane];
            float4 f2v = f2p[s4 * 64 + lane];
            float nlf[4];
#pragma unroll
            for (int a = 0; a < 4; ++a) {
                float t1 = lse4f(p1[a * 4 + 0] + f.x, p1[a * 4 + 1] + f.y,
                                 p1[a * 4 + 2] + f.z, p1[a * 4 + 3] + f.w);
                float t2 = lse4f(p2[a * 4 + 0] + f2v.x, p2[a * 4 + 1] + f2v.y,
                                 p2[a * 4 + 2] + f2v.z, p2[a * 4 + 3] + f2v.w);
                nlf[a] = t1 + t2;
            }
            acc += (double)lse4f(nlf[0] + ls0, nlf[1] + ls1, nlf[2] + ls2, nlf[3] + ls3);
        }
#pragma unroll
        for (int m = 32; m; m >>= 1) acc += __shfl_xor(acc, m, 64);
        if (lane == 0) ws[WS_NEWLL + z] = (float)acc;
    }
}

// ============ Kernel 2: per-particle finalize (1 wave per k) ============
__global__ __launch_bounds__(64) void k_finalize(
    const int* __restrict__ indexes, const int* __restrict__ m1_Kr,
    const int* __restrict__ m2_Kr, const float* __restrict__ b1_Kr,
    const float* __restrict__ b2_Kr, const int* __restrict__ lc_Kt,
    const int* __restrict__ h_Kt, const float* __restrict__ logpi_K,
    const int* __restrict__ idx1_KJ, const int* __restrict__ idx2_KJ,
    const float* __restrict__ br1_KJ, const float* __restrict__ br2_KJ,
    const float* __restrict__ logvp_KJ, const float* __restrict__ gumbel_KJ,
    const float* __restrict__ ldf, float* __restrict__ ws, float* __restrict__ out) {
    int k = blockIdx.x;
    int lane = threadIdx.x;
    int src = indexes[k];

    double nll = 0.0, topo = 0.0, sb1 = 0.0, sb2 = 0.0;
    int cnt = 0;
    if (lane < T_) {
        nll = (double)ws[WS_NODE + k * T_ + lane];
        int lc = lc_Kt[src * T_ + lane];
        int di = 2 * lc - 3; di = max(0, min(NDF_ - 1, di));
        topo = (double)ldf[di];
        cnt = (lc > 1) ? 1 : 0;
        sb1 = (double)b1_Kr[src * R_ + lane];
        sb2 = (double)b2_Kr[src * R_ + lane];
    }
    for (int o = 32; o > 0; o >>= 1) {
        nll += __shfl_down(nll, o, 64);
        topo += __shfl_down(topo, o, 64);
        sb1 += __shfl_down(sb1, o, 64);
        sb2 += __shfl_down(sb2, o, 64);
        cnt += __shfl_down(cnt, o, 64);
    }
    // broadcast reduction results to all lanes
    nll = __shfl(nll, 0, 64); topo = __shfl(topo, 0, 64);
    sb1 = __shfl(sb1, 0, 64); sb2 = __shfl(sb2, 0, 64);
    cnt = __shfl(cnt, 0, 64);
    double total_ll = nll, base_topo = -topo;
    const double lr = log(10.0);

    // lanes 0..3 each handle one proposal j (parallelizes the old serial loop)
    double lwj = 0.0, lpnj = 0.0, llikj = 0.0;
    if (lane < J_) {
        int j = lane, z = k * J_ + j;
        int i1 = idx1_KJ[z], i2 = idx2_KJ[z];
        int lc1 = lc_Kt[src * T_ + i1], lc2 = lc_Kt[src * T_ + i2];
        int nlc = lc1 + lc2;
        double loglik = total_ll - (double)ws[WS_NODE + k * T_ + i1]
                      - (double)ws[WS_NODE + k * T_ + i2] + (double)ws[WS_NEWLL + z];
        double lbp = 66.0 * lr
                   - (double)RATE_ * (sb1 + (double)br1_KJ[z] + sb2 + (double)br2_KJ[z]);
        int d1 = max(0, min(NDF_ - 1, 2 * lc1 - 3));
        int d2 = max(0, min(NDF_ - 1, 2 * lc2 - 3));
        int dn = max(0, min(NDF_ - 1, 2 * nlc - 3));
        double lt = base_topo + (double)ldf[d1] + (double)ldf[d2] - (double)ldf[dn];
        int cntj = cnt - ((lc1 > 1) ? 1 : 0) - ((lc2 > 1) ? 1 : 0) + 1;
        double lvm = log((double)cntj);
        lpnj = loglik + lbp + lt;
        llikj = loglik;
        lwj = lpnj - (double)logpi_K[src] + lvm - (double)logvp_KJ[z];
    }
    double lw0 = __shfl(lwj, 0, 64), lw1 = __shfl(lwj, 1, 64);
    double lw2 = __shfl(lwj, 2, 64), lw3 = __shfl(lwj, 3, 64);
    double m = fmax(fmax(lw0, lw1), fmax(lw2, lw3));
    double ssum = exp(lw0 - m) + exp(lw1 - m) + exp(lw2 - m) + exp(lw3 - m);
    double logw = m + log(ssum) - log((double)J_);
    int best = 0;
    double bv = lw0 + (double)gumbel_KJ[k * J_ + 0];
    { double v = lw1 + (double)gumbel_KJ[k * J_ + 1]; if (v > bv) { bv = v; best = 1; } }
    { double v = lw2 + (double)gumbel_KJ[k * J_ + 2]; if (v > bv) { bv = v; best = 2; } }
    { double v = lw3 + (double)gumbel_KJ[k * J_ + 3]; if (v > bv) { bv = v; best = 3; } }
    double lpn_b = __shfl(lpnj, best, 64);
    double llik_b = __shfl(llikj, best, 64);
    if (lane == 0) {
        out[OFF_LPN + k] = (float)lpn_b;
        out[OFF_LW + k] = (float)logw;
        out[OFF_LL + k] = (float)llik_b;
        ((int*)(ws + WS_SUB))[k] = best;
    }

    // small outputs for the selected proposal
    int zs = k * J_ + best;
    int si1 = idx1_KJ[zs], si2 = idx2_KJ[zs];
    int mn = min(si1, si2), mx = max(si1, si2);
    for (int i = lane; i < 33; i += 64) {
        float v1, v2, fb1, fb2;
        if (i < 32) {
            v1 = (float)m1_Kr[src * R_ + i];
            v2 = (float)m2_Kr[src * R_ + i];
            fb1 = b1_Kr[src * R_ + i];
            fb2 = b2_Kr[src * R_ + i];
        } else {
            v1 = (float)si1; v2 = (float)si2;
            fb1 = br1_KJ[zs]; fb2 = br2_KJ[zs];
        }
        out[OFF_M1 + k * 33 + i] = v1;
        out[OFF_M2 + k * 33 + i] = v2;
        out[OFF_B1 + k * 33 + i] = fb1;
        out[OFF_B2 + k * 33 + i] = fb2;
    }
    for (int i = lane; i < 31; i += 64) {
        int lcv, hv;
        if (i < 30) {
            int st = i;
            if (st >= mn) ++st;
            if (st >= mx) ++st;
            lcv = lc_Kt[src * T_ + st];
            hv = h_Kt[src * T_ + st];
        } else {
            lcv = lc_Kt[src * T_ + si1] + lc_Kt[src * T_ + si2];
            int h1 = h_Kt[src * T_ + si1], h2 = h_Kt[src * T_ + si2];
            int hmn = min(h1, h2), hmx = max(h1, h2);
            unsigned int u = ((unsigned int)hmn * 1000003u + (unsigned int)hmx) * 40503u
                             + 2531011u;
            hv = (int)u;  // int32 wraparound, matches JAX
        }
        out[OFF_LC + k * 31 + i] = (float)lcv;
        out[OFF_H + k * 31 + i] = (float)hv;
    }
}

// ============ Kernel 3: wide gather/copy of the big outputs ============
// grid (9, K): grp 0..7 -> 4 LF rows each (row 30 = new-node compute)
//              grp == 8 -> embr + embt copies
__global__ __launch_bounds__(256) void k_copy(
    const int* __restrict__ indexes, const int* __restrict__ idx1_KJ,
    const int* __restrict__ idx2_KJ, const float* __restrict__ embr,
    const float* __restrict__ embt, const float* __restrict__ lf,
    const float* __restrict__ emb_KJD, const float* __restrict__ ws,
    float* __restrict__ out) {
    int grp = blockIdx.x;
    int k = blockIdx.y;
    int tid = threadIdx.x;
    int src = indexes[k];
    int sub = ((const int*)(ws + WS_SUB))[k];
    int zs = k * J_ + sub;
    int si1 = idx1_KJ[zs], si2 = idx2_KJ[zs];
    int mn = min(si1, si2), mx = max(si1, si2);

    if (grp < 8) {
        __shared__ float sP[32];
        if (grp == 7) {               // block-uniform branch: only grp 7 owns row 30
            if (tid < 32) sP[tid] = ws[WS_LOGP + zs * 32 + tid];
            __syncthreads();
        }
#pragma unroll
        for (int rr = 0; rr < 4; ++rr) {
            int row = grp * 4 + rr;
            if (row >= 31) break;
            if (row < 30) {
                int st = row;
                if (st >= mn) ++st;
                if (st >= mx) ++st;
                const float4 v = *(const float4*)&lf[((size_t)(src * T_ + st) * S_ + tid) * A_];
                *(float4*)&out[OFF_LF + ((size_t)(k * 31 + row) * S_ + tid) * A_] = v;
            } else {
                float P1[16], P2[16];
#pragma unroll
                for (int i = 0; i < 16; ++i) { P1[i] = sP[i]; P2[i] = sP[16 + i]; }
                const float4 f1 = *(const float4*)&lf[((size_t)(src * T_ + si1) * S_ + tid) * A_];
                const float4 f2 = *(const float4*)&lf[((size_t)(src * T_ + si2) * S_ + tid) * A_];
                float4 o4;
#pragma unroll
                for (int a = 0; a < 4; ++a) {
                    float t1 = lse4f(P1[a * 4 + 0] + f1.x, P1[a * 4 + 1] + f1.y,
                                     P1[a * 4 + 2] + f1.z, P1[a * 4 + 3] + f1.w);
                    float t2 = lse4f(P2[a * 4 + 0] + f2.x, P2[a * 4 + 1] + f2.y,
                                     P2[a * 4 + 2] + f2.z, P2[a * 4 + 3] + f2.w);
                    ((float*)&o4)[a] = t1 + t2;
                }
                *(float4*)&out[OFF_LF + ((size_t)(k * 31 + 30) * S_ + tid) * A_] = o4;
            }
        }
    } else {
        // embr: 33 rows x 64 floats, as float4
        for (int i = tid; i < 33 * 16; i += 256) {
            int r = i >> 4, c = i & 15;
            float4 v = (r < 32) ? *(const float4*)&embr[(src * R_ + r) * D_ + c * 4]
                                : *(const float4*)&emb_KJD[zs * D_ + c * 4];
            *(float4*)&out[OFF_EMBR + k * 33 * D_ + i * 4] = v;
        }
        // embt: 31 rows x 64 floats, as float4
        for (int i = tid; i < 31 * 16; i += 256) {
            int t = i >> 4, c = i & 15;
            float4 v;
            if (t < 30) {
                int st = t;
                if (st >= mn) ++st;
                if (st >= mx) ++st;
                v = *(const float4*)&embt[(src * T_ + st) * D_ + c * 4];
            } else {
                v = *(const float4*)&emb_KJD[zs * D_ + c * 4];
            }
            *(float4*)&out[OFF_EMBT + k * 31 * D_ + i * 4] = v;
        }
    }
}

extern "C" void kernel_launch(void* const* d_in, const int* in_sizes, int n_in,
                              void* d_out, int out_size, void* d_ws, size_t ws_size,
                              hipStream_t stream) {
    const int* indexes   = (const int*)d_in[0];
    const int* m1_Kr     = (const int*)d_in[1];
    const int* m2_Kr     = (const int*)d_in[2];
    const float* b1_Kr   = (const float*)d_in[3];
    const float* b2_Kr   = (const float*)d_in[4];
    const float* embr    = (const float*)d_in[5];
    const int* lc_Kt     = (const int*)d_in[6];
    const int* h_Kt      = (const int*)d_in[7];
    const float* embt    = (const float*)d_in[8];
    const float* lf      = (const float*)d_in[9];
    const float* logpi_K = (const float*)d_in[10];
    const int* idx1_KJ   = (const int*)d_in[11];
    const int* idx2_KJ   = (const int*)d_in[12];
    const float* br1_KJ  = (const float*)d_in[13];
    const float* br2_KJ  = (const float*)d_in[14];
    const float* emb_KJD = (const float*)d_in[15];
    const float* logvp_KJ = (const float*)d_in[16];
    const float* gumbel_KJ = (const float*)d_in[17];
    const float* Wq      = (const float*)d_in[18];
    const float* Wstat   = (const float*)d_in[19];
    const float* ldf     = (const float*)d_in[20];
    float* out = (float*)d_out;
    float* ws = (float*)d_ws;

    k_compute<<<dim3(9, K_), 256, 0, stream>>>(indexes, embt, lf, Wstat, Wq,
                                               idx1_KJ, idx2_KJ, br1_KJ, br2_KJ,
                                               emb_KJD, ws);
    k_finalize<<<K_, 64, 0, stream>>>(indexes, m1_Kr, m2_Kr, b1_Kr, b2_Kr,
                                      lc_Kt, h_Kt, logpi_K, idx1_KJ, idx2_KJ,
                                      br1_KJ, br2_KJ, logvp_KJ, gumbel_KJ,
                                      ldf, ws, out);
    k_copy<<<dim3(9, K_), 256, 0, stream>>>(indexes, idx1_KJ, idx2_KJ, embr,
                                            embt, lf, emb_KJD, ws, out);
}

// Round 3
// 130.338 us; speedup vs baseline: 1.1220x; 1.0192x over previous
//
#include <hip/hip_runtime.h>
#include <math.h>

// Problem dims
constexpr int K_ = 128, J_ = 4, R_ = 32, T_ = 32, S_ = 256, A_ = 4, D_ = 64;
constexpr int NDF_ = 128;          // 2N
constexpr float RATE_ = 10.0f;     // 1/PRIOR_BL

// Output offsets (float elements) in return order
constexpr int OFF_M1   = 0;                       // K x 33 (int->float)
constexpr int OFF_M2   = OFF_M1 + K_ * 33;
constexpr int OFF_B1   = OFF_M2 + K_ * 33;
constexpr int OFF_B2   = OFF_B1 + K_ * 33;
constexpr int OFF_EMBR = OFF_B2 + K_ * 33;        // K x 33 x 64
constexpr int OFF_LC   = OFF_EMBR + K_ * 33 * D_; // K x 31
constexpr int OFF_H    = OFF_LC + K_ * 31;
constexpr int OFF_EMBT = OFF_H + K_ * 31;         // K x 31 x 64
constexpr int OFF_LF   = OFF_EMBT + K_ * 31 * D_; // K x 31 x 256 x 4
constexpr int OFF_LPN  = OFF_LF + K_ * 31 * S_ * A_;
constexpr int OFF_LW   = OFF_LPN + K_;
constexpr int OFF_LL   = OFF_LW + K_;

// Workspace layout (float elements)
constexpr int WS_NODE  = 0;                        // K*T node log-liks
constexpr int WS_NEWLL = WS_NODE + K_ * T_;        // K*J new-node log-liks
constexpr int WS_LOGP  = WS_NEWLL + K_ * J_;       // K*J*32 logP1|logP2

// fast 4-way logsumexp: hardware exp/log
__device__ inline float lse4f(float a, float b, float c, float d) {
    float m = fmaxf(fmaxf(a, b), fmaxf(c, d));
    return m + __logf(__expf(a - m) + __expf(b - m) + __expf(c - m) + __expf(d - m));
}

// ============ Kernel 1: node log-liks + proposal log-liks ============
// grid (9, K): grp 0..7 -> node blocks (wave w owns t = grp*4+w)
//              grp == 8 -> proposal block (wave w owns proposal j = w)
__global__ __launch_bounds__(256) void k_compute(
    const int* __restrict__ indexes, const float* __restrict__ embt,
    const float* __restrict__ lf, const float* __restrict__ Wstat,
    const float* __restrict__ Wq, const int* __restrict__ idx1_KJ,
    const int* __restrict__ idx2_KJ, const float* __restrict__ br1_KJ,
    const float* __restrict__ br2_KJ, const float* __restrict__ emb_KJD,
    float* __restrict__ ws) {
    int grp = blockIdx.x;
    int k = blockIdx.y;
    int tid = threadIdx.x, w = tid >> 6, lane = tid & 63;
    int src = indexes[k];

    if (grp < 8) {
        // -------- node log-lik for t = grp*4 + w --------
        int t = grp * 4 + w;
        float e = embt[(src * T_ + t) * D_ + lane];
        const float4 w4 = *(const float4*)&Wstat[lane * 4];
        float g0 = e * w4.x, g1 = e * w4.y, g2 = e * w4.z, g3 = e * w4.w;
#pragma unroll
        for (int m = 32; m; m >>= 1) {
            g0 += __shfl_xor(g0, m, 64);
            g1 += __shfl_xor(g1, m, 64);
            g2 += __shfl_xor(g2, m, 64);
            g3 += __shfl_xor(g3, m, 64);
        }
        float lse = lse4f(g0, g1, g2, g3);
        float ls0 = g0 - lse, ls1 = g1 - lse, ls2 = g2 - lse, ls3 = g3 - lse;
        const float4* fr = (const float4*)&lf[(size_t)(src * T_ + t) * S_ * A_];
        double acc = 0.0;
#pragma unroll
        for (int s4 = 0; s4 < 4; ++s4) {
            float4 f = fr[s4 * 64 + lane];   // coalesced: 1KB per instruction
            acc += (double)lse4f(f.x + ls0, f.y + ls1, f.z + ls2, f.w + ls3);
        }
#pragma unroll
        for (int m = 32; m; m >>= 1) acc += __shfl_xor(acc, m, 64);
        if (lane == 0) ws[WS_NODE + k * T_ + t] = (float)acc;
    } else {
        // -------- proposal z = k*J + w --------
        int z = k * J_ + w;
        int i1 = idx1_KJ[z], i2 = idx2_KJ[z];

        // 20 logits (16 Wq + 4 Wstat) via one butterfly
        float emb_d = emb_KJD[z * D_ + lane];
        float lg[20];
        const float4* wqr = (const float4*)&Wq[lane * 16];
        float4 q0 = wqr[0], q1 = wqr[1], q2 = wqr[2], q3 = wqr[3];
        lg[0] = emb_d * q0.x;  lg[1] = emb_d * q0.y;  lg[2] = emb_d * q0.z;  lg[3] = emb_d * q0.w;
        lg[4] = emb_d * q1.x;  lg[5] = emb_d * q1.y;  lg[6] = emb_d * q1.z;  lg[7] = emb_d * q1.w;
        lg[8] = emb_d * q2.x;  lg[9] = emb_d * q2.y;  lg[10] = emb_d * q2.z; lg[11] = emb_d * q2.w;
        lg[12] = emb_d * q3.x; lg[13] = emb_d * q3.y; lg[14] = emb_d * q3.z; lg[15] = emb_d * q3.w;
        const float4 ws4 = *(const float4*)&Wstat[lane * 4];
        lg[16] = emb_d * ws4.x; lg[17] = emb_d * ws4.y; lg[18] = emb_d * ws4.z; lg[19] = emb_d * ws4.w;
#pragma unroll
        for (int m = 32; m; m >>= 1) {
#pragma unroll
            for (int p = 0; p < 20; ++p) lg[p] += __shfl_xor(lg[p], m, 64);
        }

        float lseS = lse4f(lg[16], lg[17], lg[18], lg[19]);
        float ls0 = lg[16] - lseS, ls1 = lg[17] - lseS, ls2 = lg[18] - lseS, ls3 = lg[19] - lseS;

        // expm (f32, fixed 2^-6 scaling + Taylor-10 + 6 squarings) on lanes 0..7
        float lv[4] = {0.f, 0.f, 0.f, 0.f};
        if (lane < 8) {
            int h = lane >> 2, r = lane & 3, base = h * 4;
            float q[16];
#pragma unroll
            for (int i = 0; i < 4; ++i) {
                float rs = 0.f;
#pragma unroll
                for (int j = 0; j < 4; ++j) {
                    if (i != j) {
                        float x = lg[i * 4 + j];
                        float sp = (x > 15.f) ? x : log1pf(__expf(x));
                        q[i * 4 + j] = sp;
                        rs += sp;
                    }
                }
                q[i * 4 + i] = -rs;
            }
            float br = (h == 0) ? br1_KJ[z] : br2_KJ[z];
            float c = br * (1.f / 64.f);
#pragma unroll
            for (int e2 = 0; e2 < 16; ++e2) q[e2] *= c;
            float trow[4], arow[4];
#pragma unroll
            for (int j = 0; j < 4; ++j) { trow[j] = (j == r) ? 1.f : 0.f; arow[j] = trow[j]; }
            const float inv_n[11] = {0.f, 1.f, 0.5f, 1.f / 3.f, 0.25f, 0.2f,
                                     1.f / 6.f, 1.f / 7.f, 0.125f, 1.f / 9.f, 0.1f};
#pragma unroll
            for (int n = 1; n <= 10; ++n) {
                float nt[4];
#pragma unroll
                for (int j = 0; j < 4; ++j)
                    nt[j] = (trow[0] * q[0 * 4 + j] + trow[1] * q[1 * 4 + j] +
                             trow[2] * q[2 * 4 + j] + trow[3] * q[3 * 4 + j]) * inv_n[n];
#pragma unroll
                for (int j = 0; j < 4; ++j) { trow[j] = nt[j]; arow[j] += nt[j]; }
            }
#pragma unroll
            for (int sq = 0; sq < 6; ++sq) {
                float nrow[4];
#pragma unroll
                for (int j = 0; j < 4; ++j) {
                    float aj = arow[j];
                    nrow[j] = arow[0] * __shfl(aj, base + 0, 64)
                            + arow[1] * __shfl(aj, base + 1, 64)
                            + arow[2] * __shfl(aj, base + 2, 64)
                            + arow[3] * __shfl(aj, base + 3, 64);
                }
#pragma unroll
                for (int j = 0; j < 4; ++j) arow[j] = nrow[j];
            }
#pragma unroll
            for (int j = 0; j < 4; ++j) {
                lv[j] = __logf(fmaxf(arow[j], 1e-30f));
                ws[WS_LOGP + z * 32 + h * 16 + r * 4 + j] = lv[j];
            }
        }
        // broadcast logP to all lanes (p1 rows in lanes 0..3, p2 in lanes 4..7)
        float p1[16], p2[16];
#pragma unroll
        for (int r = 0; r < 4; ++r) {
#pragma unroll
            for (int j = 0; j < 4; ++j) {
                p1[r * 4 + j] = __shfl(lv[j], r, 64);
                p2[r * 4 + j] = __shfl(lv[j], 4 + r, 64);
            }
        }
        // new-node log-lik over sites
        const float4* f1p = (const float4*)&lf[(size_t)(src * T_ + i1) * S_ * A_];
        const float4* f2p = (const float4*)&lf[(size_t)(src * T_ + i2) * S_ * A_];
        double acc = 0.0;
#pragma unroll
        for (int s4 = 0; s4 < 4; ++s4) {
            float4 f = f1p[s4 * 64 + lane];
            float4 f2v = f2p[s4 * 64 + lane];
            float nlf[4];
#pragma unroll
            for (int a = 0; a < 4; ++a) {
                float t1 = lse4f(p1[a * 4 + 0] + f.x, p1[a * 4 + 1] + f.y,
                                 p1[a * 4 + 2] + f.z, p1[a * 4 + 3] + f.w);
                float t2 = lse4f(p2[a * 4 + 0] + f2v.x, p2[a * 4 + 1] + f2v.y,
                                 p2[a * 4 + 2] + f2v.z, p2[a * 4 + 3] + f2v.w);
                nlf[a] = t1 + t2;
            }
            acc += (double)lse4f(nlf[0] + ls0, nlf[1] + ls1, nlf[2] + ls2, nlf[3] + ls3);
        }
#pragma unroll
        for (int m = 32; m; m >>= 1) acc += __shfl_xor(acc, m, 64);
        if (lane == 0) ws[WS_NEWLL + z] = (float)acc;
    }
}

// ============ Kernel 2: redundant finalize + all outputs ============
// Every block recomputes the (cheap, wave-local) finalize for its particle k,
// deriving sub/zs/mn/mx locally — removes the separate k_finalize dispatch.
// grid (9, K): grp 0..7 -> 4 LF rows each (row 30 = new-node compute)
//              grp == 8 -> scalars + small outputs + embr + embt
__global__ __launch_bounds__(256) void k_out(
    const int* __restrict__ indexes, const int* __restrict__ m1_Kr,
    const int* __restrict__ m2_Kr, const float* __restrict__ b1_Kr,
    const float* __restrict__ b2_Kr, const float* __restrict__ embr,
    const int* __restrict__ lc_Kt, const int* __restrict__ h_Kt,
    const float* __restrict__ embt, const float* __restrict__ lf,
    const float* __restrict__ logpi_K, const int* __restrict__ idx1_KJ,
    const int* __restrict__ idx2_KJ, const float* __restrict__ br1_KJ,
    const float* __restrict__ br2_KJ, const float* __restrict__ emb_KJD,
    const float* __restrict__ logvp_KJ, const float* __restrict__ gumbel_KJ,
    const float* __restrict__ ldf, const float* __restrict__ ws,
    float* __restrict__ out) {
    int grp = blockIdx.x;
    int k = blockIdx.y;
    int tid = threadIdx.x, lane = tid & 63;
    int src = indexes[k];

    // ---- wave-local finalize (identical FP sequence in every wave/block) ----
    double nll = 0.0, topo = 0.0, sb1 = 0.0, sb2 = 0.0;
    int cnt = 0;
    if (lane < T_) {
        nll = (double)ws[WS_NODE + k * T_ + lane];
        int lc = lc_Kt[src * T_ + lane];
        int di = 2 * lc - 3; di = max(0, min(NDF_ - 1, di));
        topo = (double)ldf[di];
        cnt = (lc > 1) ? 1 : 0;
        sb1 = (double)b1_Kr[src * R_ + lane];
        sb2 = (double)b2_Kr[src * R_ + lane];
    }
#pragma unroll
    for (int m = 32; m; m >>= 1) {
        nll += __shfl_xor(nll, m, 64);
        topo += __shfl_xor(topo, m, 64);
        sb1 += __shfl_xor(sb1, m, 64);
        sb2 += __shfl_xor(sb2, m, 64);
        cnt += __shfl_xor(cnt, m, 64);
    }
    double total_ll = nll, base_topo = -topo;
    const double lr = log(10.0);

    // lanes 0..3 each handle one proposal j
    double lwj = 0.0, lpnj = 0.0, llikj = 0.0, scorej = -1.0e300;
    if (lane < J_) {
        int j = lane, z = k * J_ + j;
        int i1 = idx1_KJ[z], i2 = idx2_KJ[z];
        int lc1 = lc_Kt[src * T_ + i1], lc2 = lc_Kt[src * T_ + i2];
        int nlc = lc1 + lc2;
        double loglik = total_ll - (double)ws[WS_NODE + k * T_ + i1]
                      - (double)ws[WS_NODE + k * T_ + i2] + (double)ws[WS_NEWLL + z];
        double lbp = 66.0 * lr
                   - (double)RATE_ * (sb1 + (double)br1_KJ[z] + sb2 + (double)br2_KJ[z]);
        int d1 = max(0, min(NDF_ - 1, 2 * lc1 - 3));
        int d2 = max(0, min(NDF_ - 1, 2 * lc2 - 3));
        int dn = max(0, min(NDF_ - 1, 2 * nlc - 3));
        double lt = base_topo + (double)ldf[d1] + (double)ldf[d2] - (double)ldf[dn];
        int cntj = cnt - ((lc1 > 1) ? 1 : 0) - ((lc2 > 1) ? 1 : 0) + 1;
        double lvm = log((double)cntj);
        lpnj = loglik + lbp + lt;
        llikj = loglik;
        lwj = lpnj - (double)logpi_K[src] + lvm - (double)logvp_KJ[z];
        scorej = lwj + (double)gumbel_KJ[z];
    }
    double lw0 = __shfl(lwj, 0, 64), lw1 = __shfl(lwj, 1, 64);
    double lw2 = __shfl(lwj, 2, 64), lw3 = __shfl(lwj, 3, 64);
    double sc0 = __shfl(scorej, 0, 64), sc1 = __shfl(scorej, 1, 64);
    double sc2 = __shfl(scorej, 2, 64), sc3 = __shfl(scorej, 3, 64);
    int best = 0;
    double bv = sc0;
    if (sc1 > bv) { bv = sc1; best = 1; }
    if (sc2 > bv) { bv = sc2; best = 2; }
    if (sc3 > bv) { bv = sc3; best = 3; }
    int zs = k * J_ + best;
    int si1 = idx1_KJ[zs], si2 = idx2_KJ[zs];
    int mn = min(si1, si2), mx = max(si1, si2);

    if (grp < 8) {
        __shared__ float sP[32];
        if (grp == 7) {               // block-uniform branch: only grp 7 owns row 30
            if (tid < 32) sP[tid] = ws[WS_LOGP + zs * 32 + tid];
            __syncthreads();
        }
#pragma unroll
        for (int rr = 0; rr < 4; ++rr) {
            int row = grp * 4 + rr;
            if (row >= 31) break;
            if (row < 30) {
                int st = row;
                if (st >= mn) ++st;
                if (st >= mx) ++st;
                const float4 v = *(const float4*)&lf[((size_t)(src * T_ + st) * S_ + tid) * A_];
                *(float4*)&out[OFF_LF + ((size_t)(k * 31 + row) * S_ + tid) * A_] = v;
            } else {
                float P1[16], P2[16];
#pragma unroll
                for (int i = 0; i < 16; ++i) { P1[i] = sP[i]; P2[i] = sP[16 + i]; }
                const float4 f1 = *(const float4*)&lf[((size_t)(src * T_ + si1) * S_ + tid) * A_];
                const float4 f2 = *(const float4*)&lf[((size_t)(src * T_ + si2) * S_ + tid) * A_];
                float4 o4;
#pragma unroll
                for (int a = 0; a < 4; ++a) {
                    float t1 = lse4f(P1[a * 4 + 0] + f1.x, P1[a * 4 + 1] + f1.y,
                                     P1[a * 4 + 2] + f1.z, P1[a * 4 + 3] + f1.w);
                    float t2 = lse4f(P2[a * 4 + 0] + f2.x, P2[a * 4 + 1] + f2.y,
                                     P2[a * 4 + 2] + f2.z, P2[a * 4 + 3] + f2.w);
                    ((float*)&o4)[a] = t1 + t2;
                }
                *(float4*)&out[OFF_LF + ((size_t)(k * 31 + 30) * S_ + tid) * A_] = o4;
            }
        }
    } else {
        // scalars (double math already done; lane-exchange the best values)
        if (tid == 0) {
            double m = fmax(fmax(lw0, lw1), fmax(lw2, lw3));
            double ssum = exp(lw0 - m) + exp(lw1 - m) + exp(lw2 - m) + exp(lw3 - m);
            double logw = m + log(ssum) - log((double)J_);
            out[OFF_LW + k] = (float)logw;
        }
        double lpn_b = __shfl(lpnj, best, 64);
        double llik_b = __shfl(llikj, best, 64);
        if (tid == 0) {
            out[OFF_LPN + k] = (float)lpn_b;
            out[OFF_LL + k] = (float)llik_b;
        }
        // small outputs for the selected proposal
        for (int i = tid; i < 33; i += 256) {
            float v1, v2, fb1, fb2;
            if (i < 32) {
                v1 = (float)m1_Kr[src * R_ + i];
                v2 = (float)m2_Kr[src * R_ + i];
                fb1 = b1_Kr[src * R_ + i];
                fb2 = b2_Kr[src * R_ + i];
            } else {
                v1 = (float)si1; v2 = (float)si2;
                fb1 = br1_KJ[zs]; fb2 = br2_KJ[zs];
            }
            out[OFF_M1 + k * 33 + i] = v1;
            out[OFF_M2 + k * 33 + i] = v2;
            out[OFF_B1 + k * 33 + i] = fb1;
            out[OFF_B2 + k * 33 + i] = fb2;
        }
        for (int i = tid; i < 31; i += 256) {
            int lcv, hv;
            if (i < 30) {
                int st = i;
                if (st >= mn) ++st;
                if (st >= mx) ++st;
                lcv = lc_Kt[src * T_ + st];
                hv = h_Kt[src * T_ + st];
            } else {
                lcv = lc_Kt[src * T_ + si1] + lc_Kt[src * T_ + si2];
                int h1 = h_Kt[src * T_ + si1], h2 = h_Kt[src * T_ + si2];
                int hmn = min(h1, h2), hmx = max(h1, h2);
                unsigned int u = ((unsigned int)hmn * 1000003u + (unsigned int)hmx) * 40503u
                                 + 2531011u;
                hv = (int)u;  // int32 wraparound, matches JAX
            }
            out[OFF_LC + k * 31 + i] = (float)lcv;
            out[OFF_H + k * 31 + i] = (float)hv;
        }
        // embr: 33 rows x 64 floats, as float4
        for (int i = tid; i < 33 * 16; i += 256) {
            int r = i >> 4, c = i & 15;
            float4 v = (r < 32) ? *(const float4*)&embr[(src * R_ + r) * D_ + c * 4]
                                : *(const float4*)&emb_KJD[zs * D_ + c * 4];
            *(float4*)&out[OFF_EMBR + k * 33 * D_ + i * 4] = v;
        }
        // embt: 31 rows x 64 floats, as float4
        for (int i = tid; i < 31 * 16; i += 256) {
            int t = i >> 4, c = i & 15;
            float4 v;
            if (t < 30) {
                int st = t;
                if (st >= mn) ++st;
                if (st >= mx) ++st;
                v = *(const float4*)&embt[(src * T_ + st) * D_ + c * 4];
            } else {
                v = *(const float4*)&emb_KJD[zs * D_ + c * 4];
            }
            *(float4*)&out[OFF_EMBT + k * 31 * D_ + i * 4] = v;
        }
    }
}

extern "C" void kernel_launch(void* const* d_in, const int* in_sizes, int n_in,
                              void* d_out, int out_size, void* d_ws, size_t ws_size,
                              hipStream_t stream) {
    const int* indexes   = (const int*)d_in[0];
    const int* m1_Kr     = (const int*)d_in[1];
    const int* m2_Kr     = (const int*)d_in[2];
    const float* b1_Kr   = (const float*)d_in[3];
    const float* b2_Kr   = (const float*)d_in[4];
    const float* embr    = (const float*)d_in[5];
    const int* lc_Kt     = (const int*)d_in[6];
    const int* h_Kt      = (const int*)d_in[7];
    const float* embt    = (const float*)d_in[8];
    const float* lf      = (const float*)d_in[9];
    const float* logpi_K = (const float*)d_in[10];
    const int* idx1_KJ   = (const int*)d_in[11];
    const int* idx2_KJ   = (const int*)d_in[12];
    const float* br1_KJ  = (const float*)d_in[13];
    const float* br2_KJ  = (const float*)d_in[14];
    const float* emb_KJD = (const float*)d_in[15];
    const float* logvp_KJ = (const float*)d_in[16];
    const float* gumbel_KJ = (const float*)d_in[17];
    const float* Wq      = (const float*)d_in[18];
    const float* Wstat   = (const float*)d_in[19];
    const float* ldf     = (const float*)d_in[20];
    float* out = (float*)d_out;
    float* ws = (float*)d_ws;

    k_compute<<<dim3(9, K_), 256, 0, stream>>>(indexes, embt, lf, Wstat, Wq,
                                               idx1_KJ, idx2_KJ, br1_KJ, br2_KJ,
                                               emb_KJD, ws);
    k_out<<<dim3(9, K_), 256, 0, stream>>>(indexes, m1_Kr, m2_Kr, b1_Kr, b2_Kr,
                                           embr, lc_Kt, h_Kt, embt, lf, logpi_K,
                                           idx1_KJ, idx2_KJ, br1_KJ, br2_KJ,
                                           emb_KJD, logvp_KJ, gumbel_KJ, ldf,
                                           ws, out);
}